// Round 3
// baseline (490.904 us; speedup 1.0000x reference)
//
#include <hip/hip_runtime.h>
#include <hip/hip_bf16.h>

#define NN 50000
#define NE 800000

typedef unsigned int u32;
typedef unsigned short u16;

__device__ __forceinline__ float silu_f(float x) {
    return x * (1.0f / (1.0f + __expf(-x)));
}
__device__ __forceinline__ float bf2f(u16 u) {
    return __uint_as_float(((u32)u) << 16);
}
__device__ __forceinline__ u16 f2bf(float f) {
    u32 x = __float_as_uint(f);
    return (u16)((x + 0x7fffu + ((x >> 16) & 1u)) >> 16);   // RNE
}

// ---------------------------------------------------------------------------
// Sort-by-SRC machinery: histogram -> 2-level exclusive scan -> scatter ranks
// ---------------------------------------------------------------------------
__global__ __launch_bounds__(256) void k_hist(const int* __restrict__ ei, u32* __restrict__ cnt) {
    int e = blockIdx.x * 256 + threadIdx.x;
    atomicAdd(&cnt[ei[e]], 1u);                    // src = ei[0][e]
}

__global__ __launch_bounds__(256) void k_scan_a(const u32* __restrict__ cnt, u32* __restrict__ part) {
    __shared__ u32 sb[256];
    int t = threadIdx.x, i = blockIdx.x * 256 + t;
    u32 v = (i < NN) ? cnt[i] : 0u;
    sb[t] = v; __syncthreads();
    for (int off = 128; off > 0; off >>= 1) { if (t < off) sb[t] += sb[t + off]; __syncthreads(); }
    if (t == 0) part[blockIdx.x] = sb[0];
}

__global__ __launch_bounds__(256) void k_scan_b(u32* __restrict__ part, int nparts) {
    __shared__ u32 sb[256];
    int t = threadIdx.x;
    u32 v = (t < nparts) ? part[t] : 0u;
    sb[t] = v; __syncthreads();
    for (int off = 1; off < 256; off <<= 1) {
        u32 x = (t >= off) ? sb[t - off] : 0u; __syncthreads();
        sb[t] += x; __syncthreads();
    }
    if (t < nparts) part[t] = sb[t] - v;          // exclusive
}

__global__ __launch_bounds__(256) void k_scan_c(const u32* __restrict__ cnt, const u32* __restrict__ part,
                                                u32* __restrict__ rowcur) {
    __shared__ u32 sb[256];
    int t = threadIdx.x, i = blockIdx.x * 256 + t;
    u32 v = (i < NN) ? cnt[i] : 0u;
    sb[t] = v; __syncthreads();
    for (int off = 1; off < 256; off <<= 1) {
        u32 x = (t >= off) ? sb[t - off] : 0u; __syncthreads();
        sb[t] += x; __syncthreads();
    }
    if (i < NN) rowcur[i] = part[blockIdx.x] + sb[t] - v;   // exclusive prefix
}

__global__ __launch_bounds__(256) void k_scatter(const int* __restrict__ ei, u32* __restrict__ rowcur,
                                                 u32* __restrict__ rank, u32* __restrict__ sboth) {
    int e = blockIdx.x * 256 + threadIdx.x;
    u32 s_ = (u32)ei[e];
    u32 d_ = (u32)ei[NE + e];
    u32 pos = atomicAdd(&rowcur[s_], 1u);
    rank[e] = pos;
    sboth[pos] = s_ | (d_ << 16);                 // both < 65536
}

// ---------------------------------------------------------------------------
// K1: per-edge weight MLP; writes s (bf16, padded to 12) at src-sorted pos.
// ---------------------------------------------------------------------------
__global__ __launch_bounds__(256) void k_edge_mlp(
    const float* __restrict__ edge_attr,   // [NE][32]
    const float* __restrict__ edge_sh,     // [NE][9]
    const float* __restrict__ W1, const float* __restrict__ b1,
    const float* __restrict__ W2, const float* __restrict__ b2,
    const u32* __restrict__ rank,
    u16* __restrict__ s_sorted)            // [NE][12] bf16 at rank[e]
{
    __shared__ float sAttr[256 * 36];
    const int t  = threadIdx.x;
    const int e0 = blockIdx.x * 256;

    const float* ga = edge_attr + (size_t)e0 * 32;
    #pragma unroll
    for (int k = 0; k < 32; ++k) {
        int i = k * 256 + t;
        sAttr[(i >> 5) * 36 + (i & 31)] = ga[i];
    }
    __syncthreads();

    float a[32];
    #pragma unroll
    for (int q = 0; q < 8; ++q) {
        float4 v = *(const float4*)&sAttr[t * 36 + q * 4];
        a[4*q+0] = v.x; a[4*q+1] = v.y; a[4*q+2] = v.z; a[4*q+3] = v.w;
    }

    float hid[64];
    #pragma unroll
    for (int h = 0; h < 64; ++h) hid[h] = b1[h];
    for (int d = 0; d < 32; ++d) {
        const float ad = a[d];
        const float* wr = W1 + d * 64;
        #pragma unroll
        for (int h = 0; h < 64; ++h) hid[h] += ad * wr[h];
    }

    float w[9];
    #pragma unroll
    for (int m = 0; m < 9; ++m) w[m] = b2[m];
    for (int h = 0; h < 64; ++h) {
        const float hv = silu_f(hid[h]);
        const float* w2r = W2 + h * 9;
        #pragma unroll
        for (int m = 0; m < 9; ++m) w[m] += hv * w2r[m];
    }

    const size_t e = (size_t)e0 + t;
    const float* sh = edge_sh + e * 9;
    u16 sw[12];
    #pragma unroll
    for (int m = 0; m < 9; ++m) sw[m] = f2bf(sh[m] * w[m]);
    sw[9] = sw[10] = sw[11] = 0;

    u16* dp = s_sorted + (size_t)rank[e] * 12;
    ushort4 v0{sw[0], sw[1], sw[2],  sw[3]};
    ushort4 v1{sw[4], sw[5], sw[6],  sw[7]};
    ushort4 v2{sw[8], sw[9], sw[10], sw[11]};
    *(ushort4*)(dp + 0) = v0;
    *(ushort4*)(dp + 4) = v1;
    *(ushort4*)(dp + 8) = v2;
}

// ---------------------------------------------------------------------------
// K2: U[n, m*64+g] = sum_f feat[n,f] * W_tp[f, m*64+g]   (bf16 out)
// ---------------------------------------------------------------------------
__global__ __launch_bounds__(256) void k_u_gemm(
    const float* __restrict__ feat, const float* __restrict__ Wtp,
    u16* __restrict__ U)
{
    __shared__ float sF[64 * 68];
    __shared__ float sW[64 * 68];
    const int t  = threadIdx.x;
    const int j0 = blockIdx.x * 64;
    const int n0 = blockIdx.y * 64;

    #pragma unroll
    for (int k = 0; k < 16; ++k) {
        int i = k * 256 + t;
        int r = i >> 6, c = i & 63;
        int n = n0 + r;
        sF[r * 68 + c] = (n < NN) ? feat[(size_t)n * 64 + c] : 0.f;
        sW[r * 68 + c] = Wtp[(size_t)r * 576 + j0 + c];
    }
    __syncthreads();

    const int tx = t & 15, ty = t >> 4;
    float acc[4][4] = {};
    for (int f = 0; f < 64; ++f) {
        float4 bq = *(const float4*)&sW[f * 68 + tx * 4];
        #pragma unroll
        for (int i = 0; i < 4; ++i) {
            float av = sF[(ty * 4 + i) * 68 + f];
            acc[i][0] += av * bq.x;
            acc[i][1] += av * bq.y;
            acc[i][2] += av * bq.z;
            acc[i][3] += av * bq.w;
        }
    }

    #pragma unroll
    for (int i = 0; i < 4; ++i) {
        int n = n0 + ty * 4 + i;
        if (n < NN) {
            u16* ur = U + (size_t)n * 576 + j0 + tx * 4;
            #pragma unroll
            for (int j = 0; j < 4; ++j) ur[j] = f2bf(acc[i][j]);
        }
    }
}

// ---------------------------------------------------------------------------
// K3: combine, src-sorted order. Wave per sorted edge, lane = out feature.
// Consecutive waves share src -> U row L1/L2-hot.  Scatter via f32 atomics.
// ---------------------------------------------------------------------------
__global__ __launch_bounds__(256) void k_combine(
    const u32* __restrict__ sboth,         // [NE] src | dst<<16 (sorted by src)
    const u16* __restrict__ s_sorted,      // [NE][12]
    const u16* __restrict__ U,             // [NN][576]
    float* __restrict__ agg)               // [NN][64] (= d_out, zeroed)
{
    const int p    = (blockIdx.x * 256 + threadIdx.x) >> 6;
    const int lane = threadIdx.x & 63;
    const u32 sd  = sboth[p];
    const u32 src = sd & 0xFFFFu;
    const u32 dst = sd >> 16;
    const u16* sp = s_sorted + (size_t)p * 12;
    const ushort4 sa = *(const ushort4*)(sp + 0);
    const ushort4 sb = *(const ushort4*)(sp + 4);
    const u16     s8 = sp[8];
    const u16* ur = U + (size_t)src * 576 + lane;
    float m0 = bf2f(ur[0*64]), m1 = bf2f(ur[1*64]), m2 = bf2f(ur[2*64]);
    float m3 = bf2f(ur[3*64]), m4 = bf2f(ur[4*64]), m5 = bf2f(ur[5*64]);
    float m6 = bf2f(ur[6*64]), m7 = bf2f(ur[7*64]), m8 = bf2f(ur[8*64]);
    float acc;
    acc = bf2f(sa.x) * m0;
    acc = fmaf(bf2f(sa.y), m1, acc);
    acc = fmaf(bf2f(sa.z), m2, acc);
    acc = fmaf(bf2f(sa.w), m3, acc);
    acc = fmaf(bf2f(sb.x), m4, acc);
    acc = fmaf(bf2f(sb.y), m5, acc);
    acc = fmaf(bf2f(sb.z), m6, acc);
    acc = fmaf(bf2f(sb.w), m7, acc);
    acc = fmaf(bf2f(s8),   m8, acc);
    atomicAdd(agg + (size_t)dst * 64 + lane, acc * 0.25f);   // 1/sqrt(16)
}

// ---------------------------------------------------------------------------
// K4: FiLM, in-place on d_out.  One wave per node, lane = feature g.
// ---------------------------------------------------------------------------
__global__ __launch_bounds__(256) void k_film(
    const float* __restrict__ c_noise,
    const float* __restrict__ Wn1, const float* __restrict__ bn1,
    const float* __restrict__ Wn2, const float* __restrict__ bn2,
    float* __restrict__ out)
{
    const int n    = (blockIdx.x * 256 + threadIdx.x) >> 6;
    const int lane = threadIdx.x & 63;
    const float c  = c_noise[n];
    const float hid = silu_f(fmaf(c, Wn1[lane], bn1[lane]));
    float g = bn2[lane], b = bn2[64 + lane];
    for (int h = 0; h < 64; ++h) {
        const float hv = __shfl(hid, h, 64);
        g = fmaf(hv, Wn2[h * 128 + lane],      g);
        b = fmaf(hv, Wn2[h * 128 + 64 + lane], b);
    }
    const size_t i = (size_t)n * 64 + lane;
    out[i] = fmaf(out[i], 1.f + g, b);
}

// ---------------------------------------------------------------------------
extern "C" void kernel_launch(void* const* d_in, const int* in_sizes, int n_in,
                              void* d_out, int out_size, void* d_ws, size_t ws_size,
                              hipStream_t stream) {
    const float* features   = (const float*)d_in[0];
    const int*   edge_index = (const int*)  d_in[1];
    const float* edge_attr  = (const float*)d_in[2];
    const float* edge_sh    = (const float*)d_in[3];
    const float* c_noise    = (const float*)d_in[4];
    const float* W1  = (const float*)d_in[5];
    const float* b1  = (const float*)d_in[6];
    const float* W2  = (const float*)d_in[7];
    const float* b2  = (const float*)d_in[8];
    const float* Wtp = (const float*)d_in[9];
    const float* Wn1 = (const float*)d_in[10];
    const float* bn1 = (const float*)d_in[11];
    const float* Wn2 = (const float*)d_in[12];
    const float* bn2 = (const float*)d_in[13];
    float* out = (float*)d_out;

    char* ws = (char*)d_ws;
    u16* U        = (u16*)(ws);                    // 57,600,000 B
    u16* s_sorted = (u16*)(ws + 57600000);         // 19,200,000 B
    u32* rowcur   = (u32*)(ws + 76800000);         //    200,064 B
    u32* cnt      = (u32*)(ws + 77000064);         //    200,064 B
    u32* part     = (u32*)(ws + 77200128);         //      1,024 B
    u32* rank     = (u32*)(ws + 77201152);         //  3,200,000 B
    u32* sboth    = (u32*)(ws + 80401152);         //  3,200,000 B (end 83.6 MB)

    const int nparts = (NN + 255) / 256;           // 196

    hipMemsetAsync(cnt, 0, (size_t)NN * 4, stream);
    hipMemsetAsync(out, 0, (size_t)NN * 64 * sizeof(float), stream);

    k_hist   <<<NE / 256, 256, 0, stream>>>(edge_index, cnt);
    k_scan_a <<<nparts, 256, 0, stream>>>(cnt, part);
    k_scan_b <<<1, 256, 0, stream>>>(part, nparts);
    k_scan_c <<<nparts, 256, 0, stream>>>(cnt, part, rowcur);
    k_scatter<<<NE / 256, 256, 0, stream>>>(edge_index, rowcur, rank, sboth);

    k_edge_mlp<<<NE / 256, 256, 0, stream>>>(edge_attr, edge_sh, W1, b1, W2, b2, rank, s_sorted);
    k_u_gemm  <<<dim3(9, (NN + 63) / 64), 256, 0, stream>>>(features, Wtp, U);

    k_combine <<<(NE * 64) / 256, 256, 0, stream>>>(sboth, s_sorted, U, out);
    k_film    <<<(NN * 64) / 256, 256, 0, stream>>>(c_noise, Wn1, bn1, Wn2, bn2, out);
}